// Round 6
// baseline (866.790 us; speedup 1.0000x reference)
//
#include <hip/hip_runtime.h>

#define ROWS 2048
#define FLATK 33280
#define CHUNK_K 16640
#define SUBK 2080
#define NSTEP 65
#define S_DIM 520
#define SPLITP 16
#define OUT_THETA 40960
#define OUT_MU 303104
#define LOSCALE 2048.0f
#define INV_LOSCALE (1.0f/2048.0f)

typedef __attribute__((ext_vector_type(8))) _Float16 f16x8;
typedef __attribute__((ext_vector_type(4))) float f32x4;

union H16 { _Float16 h; unsigned short u; };

static __device__ __forceinline__ void split16(float v, unsigned short& hi, unsigned short& lo) {
    H16 a, b;
    a.h = (_Float16)v;
    float r = (v - (float)a.h) * LOSCALE;
    b.h = (_Float16)r;
    hi = a.u; lo = b.u;
}

// ---------------- K1: fused conv1+conv2 (VALU, 4x4 tile, 128-s tiles) -> A hi/lo f16 planes ----------------
// grid (2048 bl, 5 s-tiles), 256 thr. Chunk z covers o in [32z, 32z+32).
__global__ __launch_bounds__(256) void k_conv(const float* __restrict__ x,
                                              const float* __restrict__ w1, const float* __restrict__ b1,
                                              const float* __restrict__ w2, const float* __restrict__ b2,
                                              unsigned short* __restrict__ Ah, unsigned short* __restrict__ Al,
                                              int z) {
    __shared__ __align__(16) float xs[8 * 128];          // [ci][ss] 4 KB
    __shared__ float w1s[64 * 8];                        // [o][ci]  2 KB
    __shared__ float b1s[64];
    __shared__ float b2s[32];
    __shared__ __align__(16) float w2s[64 * 36];         // [c][o_local] stride 36, 9.2 KB
    __shared__ __align__(16) float h1s[64 * 130];        // [c][ss] stride 130, 33.3 KB

    int t = threadIdx.x;
    int bl = blockIdx.x, st = blockIdx.y;
    int s0 = st * 128;
    int obase = z * 32;

    const float* xb = x + (size_t)bl * (8 * S_DIM);
    for (int i = t; i < 1024; i += 256) {
        int ci = i >> 7, ss = i & 127;
        int s = s0 + ss;
        xs[i] = (s < S_DIM) ? xb[ci * S_DIM + s] : 0.f;
    }
    for (int i = t; i < 512; i += 256) w1s[i] = w1[i];
    for (int i = t; i < 2048; i += 256) {
        int o = i & 31, c = i >> 5;
        w2s[c * 36 + o] = w2[(obase + o) * 64 + c];
    }
    if (t < 64) b1s[t] = b1[t];
    else if (t < 96) b2s[t - 64] = b2[obase + t - 64];
    __syncthreads();

    // conv1 (fp32 VALU): h1[c][ss]
    for (int i = t; i < 8192; i += 256) {
        int c = i >> 7, ss = i & 127;
        float acc = b1s[c];
#pragma unroll
        for (int ci = 0; ci < 8; ci++) acc += w1s[c * 8 + ci] * xs[ci * 128 + ss];
        h1s[c * 130 + ss] = fmaxf(acc, 0.f);
    }
    __syncthreads();

    // conv2: 4 o x 4 s register tile
    int ty = t >> 5, tx = t & 31;
    int o0 = ty * 4, sl0 = tx * 4;

    float acc[4][4];
#pragma unroll
    for (int i = 0; i < 4; i++) {
        float bb = b2s[o0 + i];
#pragma unroll
        for (int j = 0; j < 4; j++) acc[i][j] = bb;
    }

    for (int c = 0; c < 64; c++) {
        float4 wv = *reinterpret_cast<const float4*>(&w2s[c * 36 + o0]);
        float4 hv = *reinterpret_cast<const float4*>(&h1s[c * 130 + sl0]);
        float av[4] = { wv.x, wv.y, wv.z, wv.w };
        float hvv[4] = { hv.x, hv.y, hv.z, hv.w };
#pragma unroll
        for (int i = 0; i < 4; i++)
#pragma unroll
            for (int j = 0; j < 4; j++) acc[i][j] += av[i] * hvv[j];
    }

    int s = s0 + sl0;
    if (s < S_DIM) {   // S_DIM % 4 == 0, so the whole 4-group is valid
#pragma unroll
        for (int i = 0; i < 4; i++) {
            unsigned short hh[4], ll[4];
#pragma unroll
            for (int j = 0; j < 4; j++) {
                float v = fmaxf(acc[i][j], 0.f);
                split16(v, hh[j], ll[j]);
            }
            size_t off = (size_t)bl * CHUNK_K + (size_t)(o0 + i) * S_DIM + s;
            *reinterpret_cast<ushort4*>(&Ah[off]) = make_ushort4(hh[0], hh[1], hh[2], hh[3]);
            *reinterpret_cast<ushort4*>(&Al[off]) = make_ushort4(ll[0], ll[1], ll[2], ll[3]);
        }
    }
}

// ---------------- K2: MFMA GEMM, fp16 hi/lo 3-pass, 128x64 tile, (256,1) ----------------
// grid dim3(16 rt, 4 ct, 8 sk)
__global__ __launch_bounds__(256, 1) void k_gemm(const unsigned short* __restrict__ Ah,
                                                 const unsigned short* __restrict__ Al,
                                                 const float* __restrict__ Bw,
                                                 float* __restrict__ P, int z) {
    __shared__ __align__(16) unsigned short As_h[128 * 40];
    __shared__ __align__(16) unsigned short As_l[128 * 40];
    __shared__ __align__(16) unsigned short Bs_h[64 * 40];
    __shared__ __align__(16) unsigned short Bs_l[64 * 40];

    int t = threadIdx.x;
    int rt = blockIdx.x, ct = blockIdx.y, sk = blockIdx.z;
    int row0 = rt * 128, col0 = ct * 64;
    int kb0 = sk * SUBK;

    int arow[2], akq[2];
    const unsigned short *ApH[2], *ApL[2];
#pragma unroll
    for (int j = 0; j < 2; j++) {
        int idx = t + 256 * j;
        arow[j] = idx >> 2; akq[j] = idx & 3;
        ApH[j] = Ah + (size_t)(row0 + arow[j]) * CHUNK_K + kb0 + akq[j] * 8;
        ApL[j] = Al + (size_t)(row0 + arow[j]) * CHUNK_K + kb0 + akq[j] * 8;
    }
    int bcol[2], bkq[2];
    const float* Bp[2];
#pragma unroll
    for (int j = 0; j < 2; j++) {
        int idx = t + 256 * j;
        bcol[j] = idx >> 3; bkq[j] = idx & 7;
        Bp[j] = Bw + (size_t)(col0 + bcol[j]) * FLATK + (size_t)z * CHUNK_K + kb0 + bkq[j] * 4;
    }

    uint4 rah[2], ral[2];
    float4 rb[2];
#pragma unroll
    for (int j = 0; j < 2; j++) {
        rah[j] = *reinterpret_cast<const uint4*>(ApH[j]);
        ral[j] = *reinterpret_cast<const uint4*>(ApL[j]);
        rb[j]  = *reinterpret_cast<const float4*>(Bp[j]);
    }

    int w = t >> 6, lane = t & 63;
    int wr = (w >> 1) * 64, wc = (w & 1) * 32;
    int m = lane & 15, kg = lane >> 4;

    f32x4 acc_h[4][2], acc_m[4][2];
#pragma unroll
    for (int i = 0; i < 4; i++)
#pragma unroll
        for (int j = 0; j < 2; j++) {
            acc_h[i][j] = (f32x4){0.f, 0.f, 0.f, 0.f};
            acc_m[i][j] = (f32x4){0.f, 0.f, 0.f, 0.f};
        }

    for (int it = 0; it < NSTEP; ++it) {
        __syncthreads();
#pragma unroll
        for (int j = 0; j < 2; j++) {
            *reinterpret_cast<uint4*>(&As_h[arow[j] * 40 + akq[j] * 8]) = rah[j];
            *reinterpret_cast<uint4*>(&As_l[arow[j] * 40 + akq[j] * 8]) = ral[j];
            float4 v = rb[j];
            unsigned short h0, h1, h2, h3, l0, l1, l2, l3;
            split16(v.x, h0, l0); split16(v.y, h1, l1);
            split16(v.z, h2, l2); split16(v.w, h3, l3);
            *reinterpret_cast<ushort4*>(&Bs_h[bcol[j] * 40 + bkq[j] * 4]) = make_ushort4(h0, h1, h2, h3);
            *reinterpret_cast<ushort4*>(&Bs_l[bcol[j] * 40 + bkq[j] * 4]) = make_ushort4(l0, l1, l2, l3);
        }
        __syncthreads();

        if (it + 1 < NSTEP) {
#pragma unroll
            for (int j = 0; j < 2; j++) {
                ApH[j] += 32; ApL[j] += 32; Bp[j] += 32;
                rah[j] = *reinterpret_cast<const uint4*>(ApH[j]);
                ral[j] = *reinterpret_cast<const uint4*>(ApL[j]);
                rb[j]  = *reinterpret_cast<const float4*>(Bp[j]);
            }
        }

        f16x8 a_h[4], a_l[4], b_h[2], b_l[2];
#pragma unroll
        for (int i = 0; i < 4; i++) {
            int off = (wr + i * 16 + m) * 40 + kg * 8;
            a_h[i] = *reinterpret_cast<const f16x8*>(&As_h[off]);
            a_l[i] = *reinterpret_cast<const f16x8*>(&As_l[off]);
        }
#pragma unroll
        for (int j = 0; j < 2; j++) {
            int off = (wc + j * 16 + m) * 40 + kg * 8;
            b_h[j] = *reinterpret_cast<const f16x8*>(&Bs_h[off]);
            b_l[j] = *reinterpret_cast<const f16x8*>(&Bs_l[off]);
        }
#pragma unroll
        for (int i = 0; i < 4; i++)
#pragma unroll
            for (int j = 0; j < 2; j++) {
                acc_h[i][j] = __builtin_amdgcn_mfma_f32_16x16x32_f16(a_h[i], b_h[j], acc_h[i][j], 0, 0, 0);
                acc_m[i][j] = __builtin_amdgcn_mfma_f32_16x16x32_f16(a_l[i], b_h[j], acc_m[i][j], 0, 0, 0);
                acc_m[i][j] = __builtin_amdgcn_mfma_f32_16x16x32_f16(a_h[i], b_l[j], acc_m[i][j], 0, 0, 0);
            }
    }

    float* Pp = P + (size_t)(z * 8 + sk) * (ROWS * 256);
    int rbase = row0 + wr + (lane >> 4) * 4;
    int cbase = col0 + wc + (lane & 15);
#pragma unroll
    for (int i = 0; i < 4; i++)
#pragma unroll
        for (int j = 0; j < 2; j++)
#pragma unroll
            for (int r = 0; r < 4; r++) {
                int rr = rbase + i * 16 + r;
                int cc = cbase + j * 16;
                Pp[(size_t)rr * 256 + cc] = acc_h[i][j][r] + acc_m[i][j][r] * INV_LOSCALE;
            }
}

// ---------------- K3: reduce + bias + relu + pl2 + Theta ----------------
__global__ __launch_bounds__(128) void k_head(const float* __restrict__ P,
                                              const float* __restrict__ pl1b,
                                              const float* __restrict__ pl2w,
                                              const float* __restrict__ pl2b,
                                              float* __restrict__ out) {
    __shared__ __align__(16) float hs[256];
    __shared__ float Rls[128];
    int row = blockIdx.x;
    int t = threadIdx.x;
    for (int c = t; c < 256; c += 128) {
        float v = pl1b[c];
#pragma unroll
        for (int zz = 0; zz < SPLITP; zz++) v += P[(size_t)zz * (ROWS * 256) + (size_t)row * 256 + c];
        hs[c] = fmaxf(v, 0.f);
    }
    __syncthreads();
    {
        float v = pl2b[t];
        const float4* wr = reinterpret_cast<const float4*>(pl2w + (size_t)t * 256);
        const float4* hv = reinterpret_cast<const float4*>(hs);
#pragma unroll 8
        for (int c4 = 0; c4 < 64; c4++) {
            float4 wq = wr[c4], h = hv[c4];
            v += wq.x * h.x + wq.y * h.y + wq.z * h.z + wq.w * h.w;
        }
        Rls[t] = v;
    }
    __syncthreads();
    if (t < 64) {
        float pr = Rls[t], pi = Rls[64 + t];
        float nrm = fmaxf(sqrtf(pr * pr + pi * pi), 1e-12f);
        float* th = out + OUT_THETA + (size_t)row * 128 + t * 2;
        th[0] = pr / nrm;
        th[1] = pi / nrm;
    }
}

// ---------------- K4: einsums + MLPs + softmax + norm ----------------
__global__ __launch_bounds__(256) void k_tail(const float* __restrict__ Hre, const float* __restrict__ Him,
                                              const float* __restrict__ chre, const float* __restrict__ chim,
                                              const float* __restrict__ b1w, const float* __restrict__ b1b,
                                              const float* __restrict__ b2w, const float* __restrict__ b2b,
                                              const float* __restrict__ b3w, const float* __restrict__ b3b,
                                              const float* __restrict__ p1w, const float* __restrict__ p1b,
                                              const float* __restrict__ p2w, const float* __restrict__ p2b,
                                              float* __restrict__ out) {
    int b = blockIdx.x, t = threadIdx.x;
    __shared__ float trs[256], tis[256];
    __shared__ float red[512];
    __shared__ __align__(16) float cH[64];
    __shared__ __align__(16) float u1[128];
    __shared__ __align__(16) float u2[128];
    __shared__ __align__(16) float q1[128];
    __shared__ float wv[80];
    __shared__ float sc[4];

    const float* th = out + OUT_THETA + (size_t)b * 512;
    for (int i = t; i < 256; i += 256) { trs[i] = th[2 * i]; tis[i] = th[2 * i + 1]; }
    __syncthreads();

    {
        int part = t >> 5, km = t & 31, k = km >> 3, m = km & 7;
        const float* hr = Hre + (size_t)b * 8192 + m * 1024 + k;
        const float* hi = Him + (size_t)b * 8192 + m * 1024 + k;
        float a1 = 0.f, a2 = 0.f;
        for (int n = part * 8; n < part * 8 + 8; n++) {
#pragma unroll
            for (int l = 0; l < 4; l++) {
                float re = hr[n * 16 + l * 4], im = hi[n * 16 + l * 4];
                float tr = trs[l * 64 + n], ti = tis[l * 64 + n];
                a1 += re * tr + im * ti;
                a2 += re * ti - im * tr;
            }
        }
        red[(part * 32 + km) * 2 + 0] = a1;
        red[(part * 32 + km) * 2 + 1] = a2;
    }
    __syncthreads();
    if (t < 32) {
        float top = 0.f, bot = 0.f;
#pragma unroll
        for (int p = 0; p < 8; p++) { top += red[(p * 32 + t) * 2]; bot += red[(p * 32 + t) * 2 + 1]; }
        int k2 = t >> 3, m2 = t & 7;
        cH[k2 * 16 + m2]     = top + chre[b * 32 + t];
        cH[k2 * 16 + 8 + m2] = bot + chim[b * 32 + t];
    }
    __syncthreads();

    const float4* ch4 = reinterpret_cast<const float4*>(cH);
    if (t < 128) {
        float v = b1b[t];
        const float4* wq = reinterpret_cast<const float4*>(b1w + (size_t)t * 64);
#pragma unroll
        for (int j = 0; j < 16; j++) {
            float4 a = wq[j], c = ch4[j];
            v += a.x * c.x + a.y * c.y + a.z * c.z + a.w * c.w;
        }
        u1[t] = fmaxf(v, 0.f);
    } else {
        int o = t - 128;
        float v = p1b[o];
        const float4* wq = reinterpret_cast<const float4*>(p1w + (size_t)o * 64);
#pragma unroll
        for (int j = 0; j < 16; j++) {
            float4 a = wq[j], c = ch4[j];
            v += a.x * c.x + a.y * c.y + a.z * c.z + a.w * c.w;
        }
        q1[o] = fmaxf(v, 0.f);
    }
    __syncthreads();

    if (t < 128) {
        float v = b2b[t];
        const float4* wq = reinterpret_cast<const float4*>(b2w + (size_t)t * 128);
        const float4* uu = reinterpret_cast<const float4*>(u1);
#pragma unroll
        for (int j = 0; j < 32; j++) {
            float4 a = wq[j], c = uu[j];
            v += a.x * c.x + a.y * c.y + a.z * c.z + a.w * c.w;
        }
        u2[t] = fmaxf(v, 0.f);
    } else if (t < 130) {
        int o = t - 128;
        float v = p2b[o];
        const float4* wq = reinterpret_cast<const float4*>(p2w + (size_t)o * 128);
        const float4* qq = reinterpret_cast<const float4*>(q1);
#pragma unroll
        for (int j = 0; j < 32; j++) {
            float4 a = wq[j], c = qq[j];
            v += a.x * c.x + a.y * c.y + a.z * c.z + a.w * c.w;
        }
        sc[o] = v;
    }
    __syncthreads();

    if (t < 80) {
        float v = b3b[t];
        const float4* wq = reinterpret_cast<const float4*>(b3w + (size_t)t * 128);
        const float4* uu = reinterpret_cast<const float4*>(u2);
#pragma unroll
        for (int j = 0; j < 32; j++) {
            float4 a = wq[j], c = uu[j];
            v += a.x * c.x + a.y * c.y + a.z * c.z + a.w * c.w;
        }
        wv[t] = v;
    }
    __syncthreads();

    if (t == 0) {
        float mx = fmaxf(sc[0], sc[1]);
        float e0 = expf(sc[0] - mx), e1 = expf(sc[1] - mx);
        float s = e0 + e1;
        float mu0 = e0 / s, mu1 = e1 / s;
        out[OUT_MU + b * 2]     = mu0;
        out[OUT_MU + b * 2 + 1] = mu1;
        float ss = 0.f;
        for (int j = 0; j < 80; j++) ss += wv[j] * wv[j];
        float wn = fmaxf(sqrtf(ss), 1e-12f);
        sc[2] = 3.16227766017f * sqrtf(mu0) / wn;
    }
    __syncthreads();
    if (t < 80) out[b * 80 + t] = wv[t] * sc[2];
}

extern "C" void kernel_launch(void* const* d_in, const int* in_sizes, int n_in,
                              void* d_out, int out_size, void* d_ws, size_t ws_size,
                              hipStream_t stream) {
    const float* x    = (const float*)d_in[0];
    const float* Hre  = (const float*)d_in[1];
    const float* Him  = (const float*)d_in[2];
    const float* chre = (const float*)d_in[3];
    const float* chim = (const float*)d_in[4];
    const float* c1w  = (const float*)d_in[5];
    const float* c1b  = (const float*)d_in[6];
    const float* c2w  = (const float*)d_in[7];
    const float* c2b  = (const float*)d_in[8];
    const float* pl1w = (const float*)d_in[9];
    const float* pl1b = (const float*)d_in[10];
    const float* pl2w = (const float*)d_in[11];
    const float* pl2b = (const float*)d_in[12];
    const float* b1w  = (const float*)d_in[13];
    const float* b1b  = (const float*)d_in[14];
    const float* b2w  = (const float*)d_in[15];
    const float* b2b  = (const float*)d_in[16];
    const float* b3w  = (const float*)d_in[17];
    const float* b3b  = (const float*)d_in[18];
    const float* p1w  = (const float*)d_in[19];
    const float* p1b  = (const float*)d_in[20];
    const float* p2w  = (const float*)d_in[21];
    const float* p2b  = (const float*)d_in[22];
    float* out = (float*)d_out;

    char* ws = (char*)d_ws;
    unsigned short* Ah = (unsigned short*)(ws + 0);           // 68,157,440 B
    unsigned short* Al = (unsigned short*)(ws + 68157440u);   // 68,157,440 B
    float* P           = (float*)(ws + 136314880u);           // 33,554,432 B (total 169,869,312 B)

    for (int z = 0; z < 2; z++) {
        k_conv<<<dim3(2048, 5), 256, 0, stream>>>(x, c1w, c1b, c2w, c2b, Ah, Al, z);
        k_gemm<<<dim3(16, 4, 8), 256, 0, stream>>>(Ah, Al, pl1w, P, z);
    }
    k_head<<<2048, 128, 0, stream>>>(P, pl1b, pl2w, pl2b, out);
    k_tail<<<512, 256, 0, stream>>>(Hre, Him, chre, chim, b1w, b1b, b2w, b2b,
                                    b3w, b3b, p1w, p1b, p2w, p2b, out);
}

// Round 7
// 821.453 us; speedup vs baseline: 1.0552x; 1.0552x over previous
//
#include <hip/hip_runtime.h>

#define ROWS 2048
#define FLATK 33280
#define CHUNK_K 16640
#define SUBK 2080
#define NSTEP 65
#define S_DIM 520
#define SPLITP 16
#define OUT_THETA 40960
#define OUT_MU 303104
#define LOSCALE 2048.0f
#define INV_LOSCALE (1.0f/2048.0f)

typedef __attribute__((ext_vector_type(8))) _Float16 f16x8;
typedef __attribute__((ext_vector_type(4))) float f32x4;

union H16 { _Float16 h; unsigned short u; };

static __device__ __forceinline__ void split16(float v, unsigned short& hi, unsigned short& lo) {
    H16 a, b;
    a.h = (_Float16)v;
    float r = (v - (float)a.h) * LOSCALE;
    b.h = (_Float16)r;
    hi = a.u; lo = b.u;
}

// ---------------- K0: pl1_w fp32 -> f16 hi/lo planes (only when ws allows) ----------------
__global__ __launch_bounds__(256) void k_cvtB(const float4* __restrict__ in,
                                              ushort4* __restrict__ outh,
                                              ushort4* __restrict__ outl, int n4) {
    int i = blockIdx.x * 256 + threadIdx.x;
    if (i >= n4) return;
    float4 v = in[i];
    unsigned short h0, h1, h2, h3, l0, l1, l2, l3;
    split16(v.x, h0, l0); split16(v.y, h1, l1);
    split16(v.z, h2, l2); split16(v.w, h3, l3);
    outh[i] = make_ushort4(h0, h1, h2, h3);
    outl[i] = make_ushort4(l0, l1, l2, l3);
}

// ---------------- K1: fused conv1+conv2 -> A hi/lo f16 planes (R4-proven structure) ----------------
// grid (2048 bl, 9 s-tiles), 256 thr. Chunk z covers o in [32z, 32z+32).
__global__ __launch_bounds__(256) void k_conv(const float* __restrict__ x,
                                              const float* __restrict__ w1, const float* __restrict__ b1,
                                              const float* __restrict__ w2, const float* __restrict__ b2,
                                              unsigned short* __restrict__ Ah, unsigned short* __restrict__ Al,
                                              int z) {
    __shared__ __align__(16) float xs[8 * 64];       // [ci][ss]
    __shared__ float w1s[512];                       // [o][ci]
    __shared__ float b1s[64];
    __shared__ float b2s[32];
    __shared__ __align__(16) float w2s[64 * 36];     // [c][o_local 32], stride 36
    __shared__ __align__(16) float h1s[64 * 68];     // [c][ss], stride 68

    int t = threadIdx.x;
    int bl = blockIdx.x, st = blockIdx.y;
    int s0 = st * 64;
    int obase = z * 32;

    const float* xb = x + (size_t)bl * (8 * S_DIM);
    for (int i = t; i < 512; i += 256) {
        int ci = i >> 6, ss = i & 63;
        int s = s0 + ss;
        xs[i] = (s < S_DIM) ? xb[ci * S_DIM + s] : 0.f;
        w1s[i] = w1[i];
    }
    for (int i = t; i < 2048; i += 256) {
        int ol = i & 31, c = i >> 5;
        w2s[c * 36 + ol] = w2[(obase + ol) * 64 + c];
    }
    if (t < 64) b1s[t] = b1[t];
    else if (t < 96) b2s[t - 64] = b2[obase + t - 64];
    __syncthreads();

    // conv1 (fp32 VALU): h1[c][ss]
    for (int i = t; i < 4096; i += 256) {
        int c = i >> 6, ss = i & 63;
        float acc = b1s[c];
#pragma unroll
        for (int ci = 0; ci < 8; ci++) acc += w1s[c * 8 + ci] * xs[ci * 64 + ss];
        h1s[c * 68 + ss] = fmaxf(acc, 0.f);
    }
    __syncthreads();

    // conv2: 4 o x 2 s register tile over the 32 chunk channels
    int o0 = (t >> 5) * 4;       // 0..28 local
    int sl0 = (t & 31) * 2;      // 0..62
    float acc[4][2];
#pragma unroll
    for (int i = 0; i < 4; i++) { acc[i][0] = b2s[o0 + i]; acc[i][1] = acc[i][0]; }

    for (int c = 0; c < 64; c++) {
        float4 wv = *reinterpret_cast<const float4*>(&w2s[c * 36 + o0]);
        float2 hv = *reinterpret_cast<const float2*>(&h1s[c * 68 + sl0]);
        float av[4] = { wv.x, wv.y, wv.z, wv.w };
#pragma unroll
        for (int i = 0; i < 4; i++) {
            acc[i][0] += av[i] * hv.x;
            acc[i][1] += av[i] * hv.y;
        }
    }

    int s = s0 + sl0;
    if (s < S_DIM) {
#pragma unroll
        for (int i = 0; i < 4; i++) {
            float v0 = fmaxf(acc[i][0], 0.f);
            float v1 = fmaxf(acc[i][1], 0.f);
            unsigned short h0, l0, h1_, l1_;
            split16(v0, h0, l0);
            split16(v1, h1_, l1_);
            size_t off = (size_t)bl * CHUNK_K + (size_t)(o0 + i) * S_DIM + s;
            *reinterpret_cast<ushort2*>(&Ah[off]) = make_ushort2(h0, h1_);
            *reinterpret_cast<ushort2*>(&Al[off]) = make_ushort2(l0, l1_);
        }
    }
}

// ---------------- K2a: MFMA GEMM, R4-exact (in-loop B split), 64x128 tile ----------------
__global__ __launch_bounds__(256, 1) void k_gemm_is(const unsigned short* __restrict__ Ah,
                                                    const unsigned short* __restrict__ Al,
                                                    const float* __restrict__ Bw,
                                                    float* __restrict__ P, int z) {
    __shared__ __align__(16) unsigned short As_h[64 * 40];
    __shared__ __align__(16) unsigned short As_l[64 * 40];
    __shared__ __align__(16) unsigned short Bs_h[128 * 40];
    __shared__ __align__(16) unsigned short Bs_l[128 * 40];

    int t = threadIdx.x;
    int rt = blockIdx.x, ct = blockIdx.y, sk = blockIdx.z;
    int row0 = rt * 64, col0 = ct * 128;
    int kb0 = sk * SUBK;

    int sa_row = t >> 2, sa_kq = t & 3;
    const unsigned short* ApH = Ah + (size_t)(row0 + sa_row) * CHUNK_K + kb0 + sa_kq * 8;
    const unsigned short* ApL = Al + (size_t)(row0 + sa_row) * CHUNK_K + kb0 + sa_kq * 8;
    const float* Bp[4];
    int sb_col[4], sb_kq[4];
#pragma unroll
    for (int j = 0; j < 4; j++) {
        int c = t + 256 * j;
        sb_col[j] = c >> 3; sb_kq[j] = c & 7;
        Bp[j] = Bw + (size_t)(col0 + sb_col[j]) * FLATK + (size_t)z * CHUNK_K + kb0 + sb_kq[j] * 4;
    }

    uint4 ra_h = *reinterpret_cast<const uint4*>(ApH);
    uint4 ra_l = *reinterpret_cast<const uint4*>(ApL);
    float4 rb[4];
#pragma unroll
    for (int j = 0; j < 4; j++) rb[j] = *reinterpret_cast<const float4*>(Bp[j]);

    int w = t >> 6, lane = t & 63;
    int m = lane & 15, kg = lane >> 4;

    f32x4 acc_h[4][2], acc_m[4][2];
#pragma unroll
    for (int i = 0; i < 4; i++)
#pragma unroll
        for (int j = 0; j < 2; j++) {
            acc_h[i][j] = (f32x4){0.f, 0.f, 0.f, 0.f};
            acc_m[i][j] = (f32x4){0.f, 0.f, 0.f, 0.f};
        }

    for (int it = 0; it < NSTEP; ++it) {
        __syncthreads();
        *reinterpret_cast<uint4*>(&As_h[sa_row * 40 + sa_kq * 8]) = ra_h;
        *reinterpret_cast<uint4*>(&As_l[sa_row * 40 + sa_kq * 8]) = ra_l;
#pragma unroll
        for (int j = 0; j < 4; j++) {
            float4 v = rb[j];
            unsigned short h0, h1, h2, h3, l0, l1, l2, l3;
            split16(v.x, h0, l0); split16(v.y, h1, l1);
            split16(v.z, h2, l2); split16(v.w, h3, l3);
            *reinterpret_cast<ushort4*>(&Bs_h[sb_col[j] * 40 + sb_kq[j] * 4]) = make_ushort4(h0, h1, h2, h3);
            *reinterpret_cast<ushort4*>(&Bs_l[sb_col[j] * 40 + sb_kq[j] * 4]) = make_ushort4(l0, l1, l2, l3);
        }
        __syncthreads();

        if (it + 1 < NSTEP) {
            ApH += 32; ApL += 32;
            ra_h = *reinterpret_cast<const uint4*>(ApH);
            ra_l = *reinterpret_cast<const uint4*>(ApL);
#pragma unroll
            for (int j = 0; j < 4; j++) {
                Bp[j] += 32;
                rb[j] = *reinterpret_cast<const float4*>(Bp[j]);
            }
        }

        f16x8 a_h[4], a_l[4], b_h[2], b_l[2];
#pragma unroll
        for (int i = 0; i < 4; i++) {
            int off = (i * 16 + m) * 40 + kg * 8;
            a_h[i] = *reinterpret_cast<const f16x8*>(&As_h[off]);
            a_l[i] = *reinterpret_cast<const f16x8*>(&As_l[off]);
        }
#pragma unroll
        for (int j = 0; j < 2; j++) {
            int off = (w * 32 + j * 16 + m) * 40 + kg * 8;
            b_h[j] = *reinterpret_cast<const f16x8*>(&Bs_h[off]);
            b_l[j] = *reinterpret_cast<const f16x8*>(&Bs_l[off]);
        }
#pragma unroll
        for (int i = 0; i < 4; i++)
#pragma unroll
            for (int j = 0; j < 2; j++) {
                acc_h[i][j] = __builtin_amdgcn_mfma_f32_16x16x32_f16(a_h[i], b_h[j], acc_h[i][j], 0, 0, 0);
                acc_m[i][j] = __builtin_amdgcn_mfma_f32_16x16x32_f16(a_l[i], b_h[j], acc_m[i][j], 0, 0, 0);
                acc_m[i][j] = __builtin_amdgcn_mfma_f32_16x16x32_f16(a_h[i], b_l[j], acc_m[i][j], 0, 0, 0);
            }
    }

    float* Pp = P + (size_t)(z * 8 + sk) * (ROWS * 256);
    int rbase = row0 + (lane >> 4) * 4;
    int cbase = col0 + w * 32 + (lane & 15);
#pragma unroll
    for (int i = 0; i < 4; i++)
#pragma unroll
        for (int j = 0; j < 2; j++)
#pragma unroll
            for (int r = 0; r < 4; r++) {
                int rr = rbase + i * 16 + r;
                int cc = cbase + j * 16;
                Pp[(size_t)rr * 256 + cc] = acc_h[i][j][r] + acc_m[i][j][r] * INV_LOSCALE;
            }
}

// ---------------- K2b: MFMA GEMM, pre-split B planes (no VALU split in loop) ----------------
__global__ __launch_bounds__(256, 1) void k_gemm_ps(const unsigned short* __restrict__ Ah,
                                                    const unsigned short* __restrict__ Al,
                                                    const unsigned short* __restrict__ Bh,
                                                    const unsigned short* __restrict__ Bl,
                                                    float* __restrict__ P, int z) {
    __shared__ __align__(16) unsigned short As_h[64 * 40];
    __shared__ __align__(16) unsigned short As_l[64 * 40];
    __shared__ __align__(16) unsigned short Bs_h[128 * 40];
    __shared__ __align__(16) unsigned short Bs_l[128 * 40];

    int t = threadIdx.x;
    int rt = blockIdx.x, ct = blockIdx.y, sk = blockIdx.z;
    int row0 = rt * 64, col0 = ct * 128;
    int kb0 = sk * SUBK;

    int sa_row = t >> 2, sa_kq = t & 3;
    const unsigned short* ApH = Ah + (size_t)(row0 + sa_row) * CHUNK_K + kb0 + sa_kq * 8;
    const unsigned short* ApL = Al + (size_t)(row0 + sa_row) * CHUNK_K + kb0 + sa_kq * 8;
    int bcol[2], bkq[2];
    const unsigned short *BpH[2], *BpL[2];
#pragma unroll
    for (int j = 0; j < 2; j++) {
        int idx = t + 256 * j;
        bcol[j] = idx >> 2; bkq[j] = idx & 3;
        size_t off = (size_t)(col0 + bcol[j]) * FLATK + (size_t)z * CHUNK_K + kb0 + bkq[j] * 8;
        BpH[j] = Bh + off;
        BpL[j] = Bl + off;
    }

    uint4 ra_h = *reinterpret_cast<const uint4*>(ApH);
    uint4 ra_l = *reinterpret_cast<const uint4*>(ApL);
    uint4 rb_h[2], rb_l[2];
#pragma unroll
    for (int j = 0; j < 2; j++) {
        rb_h[j] = *reinterpret_cast<const uint4*>(BpH[j]);
        rb_l[j] = *reinterpret_cast<const uint4*>(BpL[j]);
    }

    int w = t >> 6, lane = t & 63;
    int m = lane & 15, kg = lane >> 4;

    f32x4 acc_h[4][2], acc_m[4][2];
#pragma unroll
    for (int i = 0; i < 4; i++)
#pragma unroll
        for (int j = 0; j < 2; j++) {
            acc_h[i][j] = (f32x4){0.f, 0.f, 0.f, 0.f};
            acc_m[i][j] = (f32x4){0.f, 0.f, 0.f, 0.f};
        }

    for (int it = 0; it < NSTEP; ++it) {
        __syncthreads();
        *reinterpret_cast<uint4*>(&As_h[sa_row * 40 + sa_kq * 8]) = ra_h;
        *reinterpret_cast<uint4*>(&As_l[sa_row * 40 + sa_kq * 8]) = ra_l;
#pragma unroll
        for (int j = 0; j < 2; j++) {
            *reinterpret_cast<uint4*>(&Bs_h[bcol[j] * 40 + bkq[j] * 8]) = rb_h[j];
            *reinterpret_cast<uint4*>(&Bs_l[bcol[j] * 40 + bkq[j] * 8]) = rb_l[j];
        }
        __syncthreads();

        if (it + 1 < NSTEP) {
            ApH += 32; ApL += 32;
            ra_h = *reinterpret_cast<const uint4*>(ApH);
            ra_l = *reinterpret_cast<const uint4*>(ApL);
#pragma unroll
            for (int j = 0; j < 2; j++) {
                BpH[j] += 32; BpL[j] += 32;
                rb_h[j] = *reinterpret_cast<const uint4*>(BpH[j]);
                rb_l[j] = *reinterpret_cast<const uint4*>(BpL[j]);
            }
        }

        f16x8 a_h[4], a_l[4], b_h[2], b_l[2];
#pragma unroll
        for (int i = 0; i < 4; i++) {
            int off = (i * 16 + m) * 40 + kg * 8;
            a_h[i] = *reinterpret_cast<const f16x8*>(&As_h[off]);
            a_l[i] = *reinterpret_cast<const f16x8*>(&As_l[off]);
        }
#pragma unroll
        for (int j = 0; j < 2; j++) {
            int off = (w * 32 + j * 16 + m) * 40 + kg * 8;
            b_h[j] = *reinterpret_cast<const f16x8*>(&Bs_h[off]);
            b_l[j] = *reinterpret_cast<const f16x8*>(&Bs_l[off]);
        }
#pragma unroll
        for (int i = 0; i < 4; i++)
#pragma unroll
            for (int j = 0; j < 2; j++) {
                acc_h[i][j] = __builtin_amdgcn_mfma_f32_16x16x32_f16(a_h[i], b_h[j], acc_h[i][j], 0, 0, 0);
                acc_m[i][j] = __builtin_amdgcn_mfma_f32_16x16x32_f16(a_l[i], b_h[j], acc_m[i][j], 0, 0, 0);
                acc_m[i][j] = __builtin_amdgcn_mfma_f32_16x16x32_f16(a_h[i], b_l[j], acc_m[i][j], 0, 0, 0);
            }
    }

    float* Pp = P + (size_t)(z * 8 + sk) * (ROWS * 256);
    int rbase = row0 + (lane >> 4) * 4;
    int cbase = col0 + w * 32 + (lane & 15);
#pragma unroll
    for (int i = 0; i < 4; i++)
#pragma unroll
        for (int j = 0; j < 2; j++)
#pragma unroll
            for (int r = 0; r < 4; r++) {
                int rr = rbase + i * 16 + r;
                int cc = cbase + j * 16;
                Pp[(size_t)rr * 256 + cc] = acc_h[i][j][r] + acc_m[i][j][r] * INV_LOSCALE;
            }
}

// ---------------- K3: reduce + bias + relu + pl2 + Theta ----------------
__global__ __launch_bounds__(128) void k_head(const float* __restrict__ P,
                                              const float* __restrict__ pl1b,
                                              const float* __restrict__ pl2w,
                                              const float* __restrict__ pl2b,
                                              float* __restrict__ out) {
    __shared__ __align__(16) float hs[256];
    __shared__ float Rls[128];
    int row = blockIdx.x;
    int t = threadIdx.x;
    for (int c = t; c < 256; c += 128) {
        float v = pl1b[c];
#pragma unroll
        for (int zz = 0; zz < SPLITP; zz++) v += P[(size_t)zz * (ROWS * 256) + (size_t)row * 256 + c];
        hs[c] = fmaxf(v, 0.f);
    }
    __syncthreads();
    {
        float v = pl2b[t];
        const float4* wr = reinterpret_cast<const float4*>(pl2w + (size_t)t * 256);
        const float4* hv = reinterpret_cast<const float4*>(hs);
#pragma unroll 8
        for (int c4 = 0; c4 < 64; c4++) {
            float4 wq = wr[c4], h = hv[c4];
            v += wq.x * h.x + wq.y * h.y + wq.z * h.z + wq.w * h.w;
        }
        Rls[t] = v;
    }
    __syncthreads();
    if (t < 64) {
        float pr = Rls[t], pi = Rls[64 + t];
        float nrm = fmaxf(sqrtf(pr * pr + pi * pi), 1e-12f);
        float* th = out + OUT_THETA + (size_t)row * 128 + t * 2;
        th[0] = pr / nrm;
        th[1] = pi / nrm;
    }
}

// ---------------- K4: einsums + MLPs + softmax + norm ----------------
__global__ __launch_bounds__(256) void k_tail(const float* __restrict__ Hre, const float* __restrict__ Him,
                                              const float* __restrict__ chre, const float* __restrict__ chim,
                                              const float* __restrict__ b1w, const float* __restrict__ b1b,
                                              const float* __restrict__ b2w, const float* __restrict__ b2b,
                                              const float* __restrict__ b3w, const float* __restrict__ b3b,
                                              const float* __restrict__ p1w, const float* __restrict__ p1b,
                                              const float* __restrict__ p2w, const float* __restrict__ p2b,
                                              float* __restrict__ out) {
    int b = blockIdx.x, t = threadIdx.x;
    __shared__ float trs[256], tis[256];
    __shared__ float red[512];
    __shared__ __align__(16) float cH[64];
    __shared__ __align__(16) float u1[128];
    __shared__ __align__(16) float u2[128];
    __shared__ __align__(16) float q1[128];
    __shared__ float wv[80];
    __shared__ float sc[4];

    const float* th = out + OUT_THETA + (size_t)b * 512;
    for (int i = t; i < 256; i += 256) { trs[i] = th[2 * i]; tis[i] = th[2 * i + 1]; }
    __syncthreads();

    {
        int part = t >> 5, km = t & 31, k = km >> 3, m = km & 7;
        const float* hr = Hre + (size_t)b * 8192 + m * 1024 + k;
        const float* hi = Him + (size_t)b * 8192 + m * 1024 + k;
        float a1 = 0.f, a2 = 0.f;
        for (int n = part * 8; n < part * 8 + 8; n++) {
#pragma unroll
            for (int l = 0; l < 4; l++) {
                float re = hr[n * 16 + l * 4], im = hi[n * 16 + l * 4];
                float tr = trs[l * 64 + n], ti = tis[l * 64 + n];
                a1 += re * tr + im * ti;
                a2 += re * ti - im * tr;
            }
        }
        red[(part * 32 + km) * 2 + 0] = a1;
        red[(part * 32 + km) * 2 + 1] = a2;
    }
    __syncthreads();
    if (t < 32) {
        float top = 0.f, bot = 0.f;
#pragma unroll
        for (int p = 0; p < 8; p++) { top += red[(p * 32 + t) * 2]; bot += red[(p * 32 + t) * 2 + 1]; }
        int k2 = t >> 3, m2 = t & 7;
        cH[k2 * 16 + m2]     = top + chre[b * 32 + t];
        cH[k2 * 16 + 8 + m2] = bot + chim[b * 32 + t];
    }
    __syncthreads();

    const float4* ch4 = reinterpret_cast<const float4*>(cH);
    if (t < 128) {
        float v = b1b[t];
        const float4* wq = reinterpret_cast<const float4*>(b1w + (size_t)t * 64);
#pragma unroll
        for (int j = 0; j < 16; j++) {
            float4 a = wq[j], c = ch4[j];
            v += a.x * c.x + a.y * c.y + a.z * c.z + a.w * c.w;
        }
        u1[t] = fmaxf(v, 0.f);
    } else {
        int o = t - 128;
        float v = p1b[o];
        const float4* wq = reinterpret_cast<const float4*>(p1w + (size_t)o * 64);
#pragma unroll
        for (int j = 0; j < 16; j++) {
            float4 a = wq[j], c = ch4[j];
            v += a.x * c.x + a.y * c.y + a.z * c.z + a.w * c.w;
        }
        q1[o] = fmaxf(v, 0.f);
    }
    __syncthreads();

    if (t < 128) {
        float v = b2b[t];
        const float4* wq = reinterpret_cast<const float4*>(b2w + (size_t)t * 128);
        const float4* uu = reinterpret_cast<const float4*>(u1);
#pragma unroll
        for (int j = 0; j < 32; j++) {
            float4 a = wq[j], c = uu[j];
            v += a.x * c.x + a.y * c.y + a.z * c.z + a.w * c.w;
        }
        u2[t] = fmaxf(v, 0.f);
    } else if (t < 130) {
        int o = t - 128;
        float v = p2b[o];
        const float4* wq = reinterpret_cast<const float4*>(p2w + (size_t)o * 128);
        const float4* qq = reinterpret_cast<const float4*>(q1);
#pragma unroll
        for (int j = 0; j < 32; j++) {
            float4 a = wq[j], c = qq[j];
            v += a.x * c.x + a.y * c.y + a.z * c.z + a.w * c.w;
        }
        sc[o] = v;
    }
    __syncthreads();

    if (t < 80) {
        float v = b3b[t];
        const float4* wq = reinterpret_cast<const float4*>(b3w + (size_t)t * 128);
        const float4* uu = reinterpret_cast<const float4*>(u2);
#pragma unroll
        for (int j = 0; j < 32; j++) {
            float4 a = wq[j], c = uu[j];
            v += a.x * c.x + a.y * c.y + a.z * c.z + a.w * c.w;
        }
        wv[t] = v;
    }
    __syncthreads();

    if (t == 0) {
        float mx = fmaxf(sc[0], sc[1]);
        float e0 = expf(sc[0] - mx), e1 = expf(sc[1] - mx);
        float s = e0 + e1;
        float mu0 = e0 / s, mu1 = e1 / s;
        out[OUT_MU + b * 2]     = mu0;
        out[OUT_MU + b * 2 + 1] = mu1;
        float ss = 0.f;
        for (int j = 0; j < 80; j++) ss += wv[j] * wv[j];
        float wn = fmaxf(sqrtf(ss), 1e-12f);
        sc[2] = 3.16227766017f * sqrtf(mu0) / wn;
    }
    __syncthreads();
    if (t < 80) out[b * 80 + t] = wv[t] * sc[2];
}

extern "C" void kernel_launch(void* const* d_in, const int* in_sizes, int n_in,
                              void* d_out, int out_size, void* d_ws, size_t ws_size,
                              hipStream_t stream) {
    const float* x    = (const float*)d_in[0];
    const float* Hre  = (const float*)d_in[1];
    const float* Him  = (const float*)d_in[2];
    const float* chre = (const float*)d_in[3];
    const float* chim = (const float*)d_in[4];
    const float* c1w  = (const float*)d_in[5];
    const float* c1b  = (const float*)d_in[6];
    const float* c2w  = (const float*)d_in[7];
    const float* c2b  = (const float*)d_in[8];
    const float* pl1w = (const float*)d_in[9];
    const float* pl1b = (const float*)d_in[10];
    const float* pl2w = (const float*)d_in[11];
    const float* pl2b = (const float*)d_in[12];
    const float* b1w  = (const float*)d_in[13];
    const float* b1b  = (const float*)d_in[14];
    const float* b2w  = (const float*)d_in[15];
    const float* b2b  = (const float*)d_in[16];
    const float* b3w  = (const float*)d_in[17];
    const float* b3b  = (const float*)d_in[18];
    const float* p1w  = (const float*)d_in[19];
    const float* p1b  = (const float*)d_in[20];
    const float* p2w  = (const float*)d_in[21];
    const float* p2b  = (const float*)d_in[22];
    float* out = (float*)d_out;

    char* ws = (char*)d_ws;
    unsigned short* Ah = (unsigned short*)(ws + 0);           //  68,157,440 B
    unsigned short* Al = (unsigned short*)(ws + 68157440u);   //  68,157,440 B
    float* P           = (float*)(ws + 136314880u);           //  33,554,432 B  (end 169,869,312)
    unsigned short* Bh = (unsigned short*)(ws + 169869312u);  //  17,039,360 B
    unsigned short* Bl = (unsigned short*)(ws + 186908672u);  //  17,039,360 B  (end 203,948,032)

    const bool presplit = (ws_size >= 203948032ull);

    if (presplit) {
        k_cvtB<<<8320, 256, 0, stream>>>((const float4*)pl1w, (ushort4*)Bh, (ushort4*)Bl, 2129920);
    }
    for (int z = 0; z < 2; z++) {
        k_conv<<<dim3(2048, 9), 256, 0, stream>>>(x, c1w, c1b, c2w, c2b, Ah, Al, z);
        if (presplit)
            k_gemm_ps<<<dim3(32, 2, 8), 256, 0, stream>>>(Ah, Al, Bh, Bl, P, z);
        else
            k_gemm_is<<<dim3(32, 2, 8), 256, 0, stream>>>(Ah, Al, pl1w, P, z);
    }
    k_head<<<2048, 128, 0, stream>>>(P, pl1b, pl2w, pl2b, out);
    k_tail<<<512, 256, 0, stream>>>(Hre, Him, chre, chim, b1w, b1b, b2w, b2b,
                                    b3w, b3b, p1w, p1b, p2w, p2b, out);
}

// Round 8
// 654.664 us; speedup vs baseline: 1.3240x; 1.2548x over previous
//
#include <hip/hip_runtime.h>

#define ROWS 2048
#define FLATK 33280
#define CHUNK_K 16640
#define SUBK 2080
#define NSTEP 65
#define S_DIM 520
#define SPLITP 16
#define OUT_THETA 40960
#define OUT_MU 303104
#define LOSCALE 2048.0f
#define INV_LOSCALE (1.0f/2048.0f)

typedef __attribute__((ext_vector_type(8))) _Float16 f16x8;
typedef __attribute__((ext_vector_type(4))) float f32x4;

union H16 { _Float16 h; unsigned short u; };

static __device__ __forceinline__ void split16(float v, unsigned short& hi, unsigned short& lo) {
    H16 a, b;
    a.h = (_Float16)v;
    float r = (v - (float)a.h) * LOSCALE;
    b.h = (_Float16)r;
    hi = a.u; lo = b.u;
}

// async global->LDS, 16B per lane; lds base must be wave-uniform
static __device__ __forceinline__ void glds16(const unsigned short* g, unsigned short* l) {
    __builtin_amdgcn_global_load_lds((const __attribute__((address_space(1))) unsigned int*)g,
                                     (__attribute__((address_space(3))) unsigned int*)l,
                                     16, 0, 0);
}

// ---------------- K0: pl1_w fp32 -> f16 hi/lo planes ----------------
__global__ __launch_bounds__(256) void k_cvtB(const float4* __restrict__ in,
                                              ushort4* __restrict__ outh,
                                              ushort4* __restrict__ outl, int n4) {
    int i = blockIdx.x * 256 + threadIdx.x;
    if (i >= n4) return;
    float4 v = in[i];
    unsigned short h0, h1, h2, h3, l0, l1, l2, l3;
    split16(v.x, h0, l0); split16(v.y, h1, l1);
    split16(v.z, h2, l2); split16(v.w, h3, l3);
    outh[i] = make_ushort4(h0, h1, h2, h3);
    outl[i] = make_ushort4(l0, l1, l2, l3);
}

// ---------------- K1: fused conv1+conv2 -> A hi/lo f16 planes (R4-proven) ----------------
__global__ __launch_bounds__(256) void k_conv(const float* __restrict__ x,
                                              const float* __restrict__ w1, const float* __restrict__ b1,
                                              const float* __restrict__ w2, const float* __restrict__ b2,
                                              unsigned short* __restrict__ Ah, unsigned short* __restrict__ Al,
                                              int z) {
    __shared__ __align__(16) float xs[8 * 64];
    __shared__ float w1s[512];
    __shared__ float b1s[64];
    __shared__ float b2s[32];
    __shared__ __align__(16) float w2s[64 * 36];
    __shared__ __align__(16) float h1s[64 * 68];

    int t = threadIdx.x;
    int bl = blockIdx.x, st = blockIdx.y;
    int s0 = st * 64;
    int obase = z * 32;

    const float* xb = x + (size_t)bl * (8 * S_DIM);
    for (int i = t; i < 512; i += 256) {
        int ci = i >> 6, ss = i & 63;
        int s = s0 + ss;
        xs[i] = (s < S_DIM) ? xb[ci * S_DIM + s] : 0.f;
        w1s[i] = w1[i];
    }
    for (int i = t; i < 2048; i += 256) {
        int ol = i & 31, c = i >> 5;
        w2s[c * 36 + ol] = w2[(obase + ol) * 64 + c];
    }
    if (t < 64) b1s[t] = b1[t];
    else if (t < 96) b2s[t - 64] = b2[obase + t - 64];
    __syncthreads();

    for (int i = t; i < 4096; i += 256) {
        int c = i >> 6, ss = i & 63;
        float acc = b1s[c];
#pragma unroll
        for (int ci = 0; ci < 8; ci++) acc += w1s[c * 8 + ci] * xs[ci * 64 + ss];
        h1s[c * 68 + ss] = fmaxf(acc, 0.f);
    }
    __syncthreads();

    int o0 = (t >> 5) * 4;
    int sl0 = (t & 31) * 2;
    float acc[4][2];
#pragma unroll
    for (int i = 0; i < 4; i++) { acc[i][0] = b2s[o0 + i]; acc[i][1] = acc[i][0]; }

    for (int c = 0; c < 64; c++) {
        float4 wv = *reinterpret_cast<const float4*>(&w2s[c * 36 + o0]);
        float2 hv = *reinterpret_cast<const float2*>(&h1s[c * 68 + sl0]);
        float av[4] = { wv.x, wv.y, wv.z, wv.w };
#pragma unroll
        for (int i = 0; i < 4; i++) {
            acc[i][0] += av[i] * hv.x;
            acc[i][1] += av[i] * hv.y;
        }
    }

    int s = s0 + sl0;
    if (s < S_DIM) {
#pragma unroll
        for (int i = 0; i < 4; i++) {
            float v0 = fmaxf(acc[i][0], 0.f);
            float v1 = fmaxf(acc[i][1], 0.f);
            unsigned short h0, l0, h1_, l1_;
            split16(v0, h0, l0);
            split16(v1, h1_, l1_);
            size_t off = (size_t)bl * CHUNK_K + (size_t)(o0 + i) * S_DIM + s;
            *reinterpret_cast<ushort2*>(&Ah[off]) = make_ushort2(h0, h1_);
            *reinterpret_cast<ushort2*>(&Al[off]) = make_ushort2(l0, l1_);
        }
    }
}

// ---------------- K2: MFMA GEMM, m97-style: global_load_lds + 128x128 tile ----------------
// grid dim3(16 rt, 2 ct, 8 sk), 256 thr. Wave-tile 64x64, fp16 hi/lo 3-pass.
__global__ __launch_bounds__(256) void k_gemm(const unsigned short* __restrict__ Ah,
                                              const unsigned short* __restrict__ Al,
                                              const unsigned short* __restrict__ Bh,
                                              const unsigned short* __restrict__ Bl,
                                              float* __restrict__ P, int z) {
    __shared__ __align__(16) unsigned short As_h[128 * 32];   // packed [row][k], 8 KB
    __shared__ __align__(16) unsigned short As_l[128 * 32];
    __shared__ __align__(16) unsigned short Bs_h[128 * 32];
    __shared__ __align__(16) unsigned short Bs_l[128 * 32];

    int t = threadIdx.x;
    int rt = blockIdx.x, ct = blockIdx.y, sk = blockIdx.z;
    int row0 = rt * 128, col0 = ct * 128;
    int kb0 = sk * SUBK;

    int w = t >> 6, lane = t & 63;

    // staging: wave w covers rows [w*16, w*16+16) and [64+w*16, ...), lane -> (row, 16B granule)
    int srow = w * 16 + (lane >> 2);
    int sg = (lane & 3) * 8;                    // ushort offset of granule
    const unsigned short* gAh0 = Ah + (size_t)(row0 + srow) * CHUNK_K + kb0 + sg;
    const unsigned short* gAl0 = Al + (size_t)(row0 + srow) * CHUNK_K + kb0 + sg;
    const unsigned short* gBh0 = Bh + (size_t)(col0 + srow) * FLATK + (size_t)z * CHUNK_K + kb0 + sg;
    const unsigned short* gBl0 = Bl + (size_t)(col0 + srow) * FLATK + (size_t)z * CHUNK_K + kb0 + sg;
    const size_t strideA64 = (size_t)64 * CHUNK_K;
    const size_t strideB64 = (size_t)64 * FLATK;
    unsigned short* lAh0 = &As_h[(w * 16) * 32];
    unsigned short* lAh1 = &As_h[(64 + w * 16) * 32];
    unsigned short* lAl0 = &As_l[(w * 16) * 32];
    unsigned short* lAl1 = &As_l[(64 + w * 16) * 32];
    unsigned short* lBh0 = &Bs_h[(w * 16) * 32];
    unsigned short* lBh1 = &Bs_h[(64 + w * 16) * 32];
    unsigned short* lBl0 = &Bs_l[(w * 16) * 32];
    unsigned short* lBl1 = &Bs_l[(64 + w * 16) * 32];

    int wr = (w >> 1) * 64, wc = (w & 1) * 64;
    int m = lane & 15, kg = lane >> 4;

    f32x4 acc_h[4][4], acc_m[4][4];
#pragma unroll
    for (int i = 0; i < 4; i++)
#pragma unroll
        for (int j = 0; j < 4; j++) {
            acc_h[i][j] = (f32x4){0.f, 0.f, 0.f, 0.f};
            acc_m[i][j] = (f32x4){0.f, 0.f, 0.f, 0.f};
        }

    for (int it = 0; it < NSTEP; ++it) {
        __syncthreads();   // previous iteration's LDS reads complete
        glds16(gAh0, lAh0);
        glds16(gAh0 + strideA64, lAh1);
        glds16(gAl0, lAl0);
        glds16(gAl0 + strideA64, lAl1);
        glds16(gBh0, lBh0);
        glds16(gBh0 + strideB64, lBh1);
        glds16(gBl0, lBl0);
        glds16(gBl0 + strideB64, lBl1);
        gAh0 += 32; gAl0 += 32; gBh0 += 32; gBl0 += 32;
        __syncthreads();   // drains vmcnt -> staged data visible

        f16x8 a_h[4], a_l[4], b_h[4], b_l[4];
#pragma unroll
        for (int i = 0; i < 4; i++) {
            int off = (wr + i * 16 + m) * 32 + kg * 8;
            a_h[i] = *reinterpret_cast<const f16x8*>(&As_h[off]);
            a_l[i] = *reinterpret_cast<const f16x8*>(&As_l[off]);
        }
#pragma unroll
        for (int j = 0; j < 4; j++) {
            int off = (wc + j * 16 + m) * 32 + kg * 8;
            b_h[j] = *reinterpret_cast<const f16x8*>(&Bs_h[off]);
            b_l[j] = *reinterpret_cast<const f16x8*>(&Bs_l[off]);
        }
#pragma unroll
        for (int i = 0; i < 4; i++)
#pragma unroll
            for (int j = 0; j < 4; j++) {
                acc_h[i][j] = __builtin_amdgcn_mfma_f32_16x16x32_f16(a_h[i], b_h[j], acc_h[i][j], 0, 0, 0);
                acc_m[i][j] = __builtin_amdgcn_mfma_f32_16x16x32_f16(a_l[i], b_h[j], acc_m[i][j], 0, 0, 0);
                acc_m[i][j] = __builtin_amdgcn_mfma_f32_16x16x32_f16(a_h[i], b_l[j], acc_m[i][j], 0, 0, 0);
            }
    }

    float* Pp = P + (size_t)(z * 8 + sk) * (ROWS * 256);
    int rbase = row0 + wr + (lane >> 4) * 4;
    int cbase = col0 + wc + (lane & 15);
#pragma unroll
    for (int i = 0; i < 4; i++)
#pragma unroll
        for (int j = 0; j < 4; j++)
#pragma unroll
            for (int r = 0; r < 4; r++) {
                int rr = rbase + i * 16 + r;
                int cc = cbase + j * 16;
                Pp[(size_t)rr * 256 + cc] = acc_h[i][j][r] + acc_m[i][j][r] * INV_LOSCALE;
            }
}

// ---------------- K3: reduce + bias + relu + pl2 + Theta ----------------
__global__ __launch_bounds__(128) void k_head(const float* __restrict__ P,
                                              const float* __restrict__ pl1b,
                                              const float* __restrict__ pl2w,
                                              const float* __restrict__ pl2b,
                                              float* __restrict__ out) {
    __shared__ __align__(16) float hs[256];
    __shared__ float Rls[128];
    int row = blockIdx.x;
    int t = threadIdx.x;
    for (int c = t; c < 256; c += 128) {
        float v = pl1b[c];
#pragma unroll
        for (int zz = 0; zz < SPLITP; zz++) v += P[(size_t)zz * (ROWS * 256) + (size_t)row * 256 + c];
        hs[c] = fmaxf(v, 0.f);
    }
    __syncthreads();
    {
        float v = pl2b[t];
        const float4* wr = reinterpret_cast<const float4*>(pl2w + (size_t)t * 256);
        const float4* hv = reinterpret_cast<const float4*>(hs);
#pragma unroll 8
        for (int c4 = 0; c4 < 64; c4++) {
            float4 wq = wr[c4], h = hv[c4];
            v += wq.x * h.x + wq.y * h.y + wq.z * h.z + wq.w * h.w;
        }
        Rls[t] = v;
    }
    __syncthreads();
    if (t < 64) {
        float pr = Rls[t], pi = Rls[64 + t];
        float nrm = fmaxf(sqrtf(pr * pr + pi * pi), 1e-12f);
        float* th = out + OUT_THETA + (size_t)row * 128 + t * 2;
        th[0] = pr / nrm;
        th[1] = pi / nrm;
    }
}

// ---------------- K4: einsums + MLPs + softmax + norm ----------------
__global__ __launch_bounds__(256) void k_tail(const float* __restrict__ Hre, const float* __restrict__ Him,
                                              const float* __restrict__ chre, const float* __restrict__ chim,
                                              const float* __restrict__ b1w, const float* __restrict__ b1b,
                                              const float* __restrict__ b2w, const float* __restrict__ b2b,
                                              const float* __restrict__ b3w, const float* __restrict__ b3b,
                                              const float* __restrict__ p1w, const float* __restrict__ p1b,
                                              const float* __restrict__ p2w, const float* __restrict__ p2b,
                                              float* __restrict__ out) {
    int b = blockIdx.x, t = threadIdx.x;
    __shared__ float trs[256], tis[256];
    __shared__ float red[512];
    __shared__ __align__(16) float cH[64];
    __shared__ __align__(16) float u1[128];
    __shared__ __align__(16) float u2[128];
    __shared__ __align__(16) float q1[128];
    __shared__ float wv[80];
    __shared__ float sc[4];

    const float* th = out + OUT_THETA + (size_t)b * 512;
    for (int i = t; i < 256; i += 256) { trs[i] = th[2 * i]; tis[i] = th[2 * i + 1]; }
    __syncthreads();

    {
        int part = t >> 5, km = t & 31, k = km >> 3, m = km & 7;
        const float* hr = Hre + (size_t)b * 8192 + m * 1024 + k;
        const float* hi = Him + (size_t)b * 8192 + m * 1024 + k;
        float a1 = 0.f, a2 = 0.f;
        for (int n = part * 8; n < part * 8 + 8; n++) {
#pragma unroll
            for (int l = 0; l < 4; l++) {
                float re = hr[n * 16 + l * 4], im = hi[n * 16 + l * 4];
                float tr = trs[l * 64 + n], ti = tis[l * 64 + n];
                a1 += re * tr + im * ti;
                a2 += re * ti - im * tr;
            }
        }
        red[(part * 32 + km) * 2 + 0] = a1;
        red[(part * 32 + km) * 2 + 1] = a2;
    }
    __syncthreads();
    if (t < 32) {
        float top = 0.f, bot = 0.f;
#pragma unroll
        for (int p = 0; p < 8; p++) { top += red[(p * 32 + t) * 2]; bot += red[(p * 32 + t) * 2 + 1]; }
        int k2 = t >> 3, m2 = t & 7;
        cH[k2 * 16 + m2]     = top + chre[b * 32 + t];
        cH[k2 * 16 + 8 + m2] = bot + chim[b * 32 + t];
    }
    __syncthreads();

    const float4* ch4 = reinterpret_cast<const float4*>(cH);
    if (t < 128) {
        float v = b1b[t];
        const float4* wq = reinterpret_cast<const float4*>(b1w + (size_t)t * 64);
#pragma unroll
        for (int j = 0; j < 16; j++) {
            float4 a = wq[j], c = ch4[j];
            v += a.x * c.x + a.y * c.y + a.z * c.z + a.w * c.w;
        }
        u1[t] = fmaxf(v, 0.f);
    } else {
        int o = t - 128;
        float v = p1b[o];
        const float4* wq = reinterpret_cast<const float4*>(p1w + (size_t)o * 64);
#pragma unroll
        for (int j = 0; j < 16; j++) {
            float4 a = wq[j], c = ch4[j];
            v += a.x * c.x + a.y * c.y + a.z * c.z + a.w * c.w;
        }
        q1[o] = fmaxf(v, 0.f);
    }
    __syncthreads();

    if (t < 128) {
        float v = b2b[t];
        const float4* wq = reinterpret_cast<const float4*>(b2w + (size_t)t * 128);
        const float4* uu = reinterpret_cast<const float4*>(u1);
#pragma unroll
        for (int j = 0; j < 32; j++) {
            float4 a = wq[j], c = uu[j];
            v += a.x * c.x + a.y * c.y + a.z * c.z + a.w * c.w;
        }
        u2[t] = fmaxf(v, 0.f);
    } else if (t < 130) {
        int o = t - 128;
        float v = p2b[o];
        const float4* wq = reinterpret_cast<const float4*>(p2w + (size_t)o * 128);
        const float4* qq = reinterpret_cast<const float4*>(q1);
#pragma unroll
        for (int j = 0; j < 32; j++) {
            float4 a = wq[j], c = qq[j];
            v += a.x * c.x + a.y * c.y + a.z * c.z + a.w * c.w;
        }
        sc[o] = v;
    }
    __syncthreads();

    if (t < 80) {
        float v = b3b[t];
        const float4* wq = reinterpret_cast<const float4*>(b3w + (size_t)t * 128);
        const float4* uu = reinterpret_cast<const float4*>(u2);
#pragma unroll
        for (int j = 0; j < 32; j++) {
            float4 a = wq[j], c = uu[j];
            v += a.x * c.x + a.y * c.y + a.z * c.z + a.w * c.w;
        }
        wv[t] = v;
    }
    __syncthreads();

    if (t == 0) {
        float mx = fmaxf(sc[0], sc[1]);
        float e0 = expf(sc[0] - mx), e1 = expf(sc[1] - mx);
        float s = e0 + e1;
        float mu0 = e0 / s, mu1 = e1 / s;
        out[OUT_MU + b * 2]     = mu0;
        out[OUT_MU + b * 2 + 1] = mu1;
        float ss = 0.f;
        for (int j = 0; j < 80; j++) ss += wv[j] * wv[j];
        float wn = fmaxf(sqrtf(ss), 1e-12f);
        sc[2] = 3.16227766017f * sqrtf(mu0) / wn;
    }
    __syncthreads();
    if (t < 80) out[b * 80 + t] = wv[t] * sc[2];
}

extern "C" void kernel_launch(void* const* d_in, const int* in_sizes, int n_in,
                              void* d_out, int out_size, void* d_ws, size_t ws_size,
                              hipStream_t stream) {
    const float* x    = (const float*)d_in[0];
    const float* Hre  = (const float*)d_in[1];
    const float* Him  = (const float*)d_in[2];
    const float* chre = (const float*)d_in[3];
    const float* chim = (const float*)d_in[4];
    const float* c1w  = (const float*)d_in[5];
    const float* c1b  = (const float*)d_in[6];
    const float* c2w  = (const float*)d_in[7];
    const float* c2b  = (const float*)d_in[8];
    const float* pl1w = (const float*)d_in[9];
    const float* pl1b = (const float*)d_in[10];
    const float* pl2w = (const float*)d_in[11];
    const float* pl2b = (const float*)d_in[12];
    const float* b1w  = (const float*)d_in[13];
    const float* b1b  = (const float*)d_in[14];
    const float* b2w  = (const float*)d_in[15];
    const float* b2b  = (const float*)d_in[16];
    const float* b3w  = (const float*)d_in[17];
    const float* b3b  = (const float*)d_in[18];
    const float* p1w  = (const float*)d_in[19];
    const float* p1b  = (const float*)d_in[20];
    const float* p2w  = (const float*)d_in[21];
    const float* p2b  = (const float*)d_in[22];
    float* out = (float*)d_out;

    char* ws = (char*)d_ws;
    unsigned short* Ah = (unsigned short*)(ws + 0);           //  68,157,440 B
    unsigned short* Al = (unsigned short*)(ws + 68157440u);   //  68,157,440 B
    float* P           = (float*)(ws + 136314880u);           //  33,554,432 B  (end 169,869,312)
    unsigned short* Bh = (unsigned short*)(ws + 169869312u);  //  17,039,360 B
    unsigned short* Bl = (unsigned short*)(ws + 186908672u);  //  17,039,360 B  (end 203,948,032; ws >= this, proven R7)

    k_cvtB<<<8320, 256, 0, stream>>>((const float4*)pl1w, (ushort4*)Bh, (ushort4*)Bl, 2129920);
    for (int z = 0; z < 2; z++) {
        k_conv<<<dim3(2048, 9), 256, 0, stream>>>(x, c1w, c1b, c2w, c2b, Ah, Al, z);
        k_gemm<<<dim3(16, 2, 8), 256, 0, stream>>>(Ah, Al, Bh, Bl, P, z);
    }
    k_head<<<2048, 128, 0, stream>>>(P, pl1b, pl2w, pl2b, out);
    k_tail<<<512, 256, 0, stream>>>(Hre, Him, chre, chim, b1w, b1b, b2w, b2b,
                                    b3w, b3b, p1w, p1b, p2w, p2b, out);
}